// Round 2
// baseline (286.848 us; speedup 1.0000x reference)
//
#include <hip/hip_runtime.h>
#include <hip/hip_bf16.h>
#include <hip/hip_cooperative_groups.h>

namespace cg = cooperative_groups;

#define N_NODES 100000
#define DEGREE 32
#define N_PAIRS 8192
#define FEAT 9
#define HID 20
#define NOUT 15
#define FPAD 16  // padded row stride (elements) for bf16 featb and t tables

#define NPB 28   // nodes per chunk in stage B (28*9 = 252 active lanes of 256)
#define PPB 8    // pairs per chunk in stage C (8*30 = 240 active lanes of 256)
#define NCHUNK_B ((N_NODES + NPB - 1) / NPB)  // 3572
#define NCHUNK_C (N_PAIRS / PPB)              // 1024

// ---------------------------------------------------------------------------
// Single cooperative kernel: stage A (feat->bf16 pad), grid.sync, stage B
// (enc1-mean + node MLP -> t), grid.sync, stage C (enc2 aggregate + pair MLP).
// Rationale: per-stage memory arithmetic says the work is ~15 us total; the
// rest of the controllable time is launch boundaries + grid tails. Merging
// removes 2 launches + K0's dispatch and overlaps stage tails.
// ---------------------------------------------------------------------------
__global__ __launch_bounds__(256, 4) void k_fused(
    const int* __restrict__ to_pred,
    const int* __restrict__ adj,
    const float* __restrict__ feat,
    const float* __restrict__ W1,     // [HID][2*FEAT]
    const float* __restrict__ W2,     // [NOUT][HID]
    const float* __restrict__ fc1_w,  // [15][30]
    const float* __restrict__ fc1_b,  // [15]
    const float* __restrict__ fc2_w,  // [1][15]
    const float* __restrict__ fc2_b,  // [1]
    __hip_bfloat16* __restrict__ featb,
    __hip_bfloat16* __restrict__ t_ws,
    float* __restrict__ out) {
  __shared__ float sW1[HID * 2 * FEAT];   // 360
  __shared__ float sW2[NOUT * HID];       // 300
  __shared__ float sComb[NPB][2 * FEAT];  // 28 x 18
  __shared__ float sH[NPB][HID];          // 28 x 20
  __shared__ float s1[15 * 30];
  __shared__ float b1v[15];
  __shared__ float s2v[15];
  __shared__ float b2v;
  __shared__ float sE[PPB][30];
  __shared__ float sHh[PPB][15];

  int tid = threadIdx.x;
  // load ALL weights once (used across grid-stride chunks)
  for (int i = tid; i < HID * 2 * FEAT; i += 256) sW1[i] = W1[i];
  for (int i = tid; i < NOUT * HID; i += 256) sW2[i] = W2[i];
  for (int i = tid; i < 15 * 30; i += 256) s1[i] = fc1_w[i];
  if (tid < 15) {
    b1v[tid] = fc1_b[tid];
    s2v[tid] = fc2_w[tid];
  }
  if (tid == 0) b2v = fc2_b[0];
  __syncthreads();

  cg::grid_group grid = cg::this_grid();

  // ---- stage A: feat [N][9] fp32 -> featb [N][16] bf16 (32B-aligned rows).
  // One row per thread; contiguous 36B reads / 32B uint4-pair writes.
  for (int n = blockIdx.x * 256 + tid; n < N_NODES; n += gridDim.x * 256) {
    const float* fr = feat + (size_t)n * FEAT;
    __hip_bfloat16 u[FPAD];
#pragma unroll
    for (int j = 0; j < FEAT; ++j) u[j] = __float2bfloat16(fr[j]);
#pragma unroll
    for (int j = FEAT; j < FPAD; ++j) u[j] = __float2bfloat16(0.f);
    uint4* dst = (uint4*)(featb + (size_t)n * FPAD);
    dst[0] = *(const uint4*)(u);
    dst[1] = *(const uint4*)(u + 8);
  }
  grid.sync();

  // ---- stage B: enc1-mean + node MLP -> t (bf16, stride FPAD)
  for (int c = blockIdx.x; c < NCHUNK_B; c += gridDim.x) {
    int base = c * NPB;

    // phase 1: [self feat (fp32) | neighbor mean (bf16 gathers)] -> sComb
    if (tid < NPB * FEAT) {
      int nl = tid / FEAT;
      int j = tid - nl * FEAT;
      int n = base + nl;
      if (n < N_NODES) {
        const int4* arow4 = (const int4*)(adj + (size_t)n * DEGREE);
        float s = 0.f;
#pragma unroll
        for (int cc = 0; cc < DEGREE / 4; ++cc) {
          int4 a4 = arow4[cc];
          s += __bfloat162float(featb[a4.x * FPAD + j]);
          s += __bfloat162float(featb[a4.y * FPAD + j]);
          s += __bfloat162float(featb[a4.z * FPAD + j]);
          s += __bfloat162float(featb[a4.w * FPAD + j]);
        }
        sComb[nl][j] = feat[(size_t)n * FEAT + j];  // self stays fp32
        sComb[nl][FEAT + j] = s * (1.0f / DEGREE);
      }
    }
    __syncthreads();

    // phase 2: h1 = relu(W1 @ comb)
    for (int idx = tid; idx < NPB * HID; idx += 256) {
      int nl = idx / HID;
      int i = idx - nl * HID;
      if (base + nl < N_NODES) {
        float acc = 0.f;
#pragma unroll
        for (int j = 0; j < 2 * FEAT; ++j)
          acc += sW1[i * 2 * FEAT + j] * sComb[nl][j];
        sH[nl][i] = fmaxf(acc, 0.f);
      }
    }
    __syncthreads();

    // phase 3: t = W2 @ h1 (linear; relu comes after enc2 mean)
    for (int idx = tid; idx < NPB * NOUT; idx += 256) {
      int nl = idx / NOUT;
      int d = idx - nl * NOUT;
      int n = base + nl;
      if (n < N_NODES) {
        float acc = 0.f;
#pragma unroll
        for (int i = 0; i < HID; ++i) acc += sW2[d * HID + i] * sH[nl][i];
        t_ws[(size_t)n * FPAD + d] = __float2bfloat16(acc);
      }
    }
    // no trailing sync needed: next iteration's phase-1 barrier orders
    // prev phase-3 reads of sH before next phase-2 writes.
    __syncthreads();
  }
  grid.sync();

  // ---- stage C: enc2 endpoint aggregation + pair MLP
  for (int c = blockIdx.x; c < NCHUNK_C; c += gridDim.x) {
    int pbase = c * PPB;

    // phase 1: endpoint aggregate (self + 32 neighbors of t, relu(mean))
    if (tid < PPB * 30) {
      int pl = tid / 30;
      int slot = tid - pl * 30;
      int side = slot / 15;
      int d = slot - side * 15;
      int p = pbase + pl;
      int node = to_pred[2 * p + side];
      const int4* arow4 = (const int4*)(adj + (size_t)node * DEGREE);
      float s = __bfloat162float(t_ws[node * FPAD + d]);  // gcn=True self
#pragma unroll
      for (int cc = 0; cc < DEGREE / 4; ++cc) {
        int4 a4 = arow4[cc];
        s += __bfloat162float(t_ws[a4.x * FPAD + d]);
        s += __bfloat162float(t_ws[a4.y * FPAD + d]);
        s += __bfloat162float(t_ws[a4.z * FPAD + d]);
        s += __bfloat162float(t_ws[a4.w * FPAD + d]);
      }
      sE[pl][slot] = fmaxf(s * (1.0f / (DEGREE + 1)), 0.f);
    }
    __syncthreads();

    // phase 2: h = relu(fc1 @ e + b1)
    if (tid < PPB * 15) {
      int pl = tid / 15;
      int i = tid - pl * 15;
      float acc = b1v[i];
#pragma unroll
      for (int j = 0; j < 30; ++j) acc += s1[i * 30 + j] * sE[pl][j];
      sHh[pl][i] = fmaxf(acc, 0.f);
    }
    __syncthreads();

    // phase 3: out = relu(fc2 @ h + b2)
    if (tid < PPB) {
      float acc = b2v;
#pragma unroll
      for (int i = 0; i < 15; ++i) acc += s2v[i] * sHh[tid][i];
      out[pbase + tid] = fmaxf(acc, 0.f);
    }
    __syncthreads();
  }
}

// ---------------------------------------------------------------------------
extern "C" void kernel_launch(void* const* d_in, const int* in_sizes, int n_in,
                              void* d_out, int out_size, void* d_ws,
                              size_t ws_size, hipStream_t stream) {
  const int* to_pred = (const int*)d_in[0];
  const int* adj     = (const int*)d_in[1];
  const float* feat  = (const float*)d_in[2];
  const float* W1    = (const float*)d_in[3];
  const float* W2    = (const float*)d_in[4];
  const float* fc1_w = (const float*)d_in[5];
  const float* fc1_b = (const float*)d_in[6];
  const float* fc2_w = (const float*)d_in[7];
  const float* fc2_b = (const float*)d_in[8];
  float* out         = (float*)d_out;

  // workspace: featb [100000][16] bf16 (3.2 MB) | t [100000][16] bf16 (3.2 MB)
  __hip_bfloat16* featb = (__hip_bfloat16*)d_ws;
  __hip_bfloat16* t_ws  = featb + (size_t)N_NODES * FPAD;

  // co-resident grid for grid.sync(): blocks/CU from the occupancy API
  // (host-side query, no stream interaction — graph-capture safe), 256 CUs.
  static int coop_grid = 0;
  if (coop_grid == 0) {
    int nb = 0;
    hipOccupancyMaxActiveBlocksPerMultiprocessor(
        &nb, reinterpret_cast<const void*>(k_fused), 256, 0);
    if (nb < 1) nb = 1;
    if (nb > 8) nb = 8;      // 8 blocks x 256 thr = 32 waves/CU cap
    coop_grid = nb * 256;    // MI355X: 256 CUs
  }

  void* params[] = {
      (void*)&to_pred, (void*)&adj, (void*)&feat, (void*)&W1, (void*)&W2,
      (void*)&fc1_w, (void*)&fc1_b, (void*)&fc2_w, (void*)&fc2_b,
      (void*)&featb, (void*)&t_ws, (void*)&out};

  hipLaunchCooperativeKernel(reinterpret_cast<const void*>(k_fused),
                             dim3(coop_grid), dim3(256), params, 0, stream);
}

// Round 3
// 130.941 us; speedup vs baseline: 2.1907x; 2.1907x over previous
//
#include <hip/hip_runtime.h>
#include <hip/hip_bf16.h>

#define N_NODES 100000
#define DEGREE 32
#define N_PAIRS 8192
#define FEAT 9
#define HID 20
#define NOUT 15
#define FPAD 16  // padded row stride (elements) for bf16 featb and t tables

// bf16 (bits in low/high half of a dword) -> f32
__device__ __forceinline__ float bflo(unsigned int w) {
  return __uint_as_float(w << 16);
}
__device__ __forceinline__ float bfhi(unsigned int w) {
  return __uint_as_float(w & 0xffff0000u);
}

// ---------------------------------------------------------------------------
// K0: prep — feat [N][9] fp32 -> featb [N][16] bf16 (32B-aligned rows).
// One row per thread, vector uint4 stores.
// ---------------------------------------------------------------------------
__global__ __launch_bounds__(256) void k_prep(
    const float* __restrict__ feat, __hip_bfloat16* __restrict__ featb) {
  int n = blockIdx.x * 256 + threadIdx.x;
  if (n < N_NODES) {
    const float* fr = feat + (size_t)n * FEAT;
    __hip_bfloat16 u[FPAD];
#pragma unroll
    for (int j = 0; j < FEAT; ++j) u[j] = __float2bfloat16(fr[j]);
#pragma unroll
    for (int j = FEAT; j < FPAD; ++j) u[j] = __float2bfloat16(0.f);
    uint4* dst = (uint4*)(featb + (size_t)n * FPAD);
    dst[0] = *(const uint4*)(u);
    dst[1] = *(const uint4*)(u + 8);
  }
}

// ---------------------------------------------------------------------------
// K1: wave-parallel enc1-mean + node MLP. One wave = 2 nodes (one per
// 32-lane half). Lane k of a half loads neighbor k's ENTIRE featb row
// (uint4 + u16, same aligned 32B line) -> 64 independent line accesses per
// load instruction (vs 8 in the thread-serial scheme). 5-step shfl_xor
// butterfly gives every lane the 9 column sums; lanes 0-19 run the W1 MLP,
// lanes 0-14 the W2 projection via a tiny wave-local LDS scratch.
// No __syncthreads in the hot path. grid*8 == N_NODES exactly (12500*8).
// ---------------------------------------------------------------------------
__global__ __launch_bounds__(256) void k_node(
    const int* __restrict__ adj,
    const float* __restrict__ feat,
    const __hip_bfloat16* __restrict__ featb,
    const float* __restrict__ W1,   // [HID][2*FEAT]
    const float* __restrict__ W2,   // [NOUT][HID]
    __hip_bfloat16* __restrict__ t_ws) {
  __shared__ float sW1[HID * 2 * FEAT];  // 360
  __shared__ float sW2[NOUT * HID];      // 300
  __shared__ float sH[4][2][HID];        // per-(wave,half) h1 scratch

  int tid = threadIdx.x;
  for (int i = tid; i < HID * 2 * FEAT; i += 256) sW1[i] = W1[i];
  for (int i = tid; i < NOUT * HID; i += 256) sW2[i] = W2[i];
  __syncthreads();  // weights only; hot path below is wave-local

  int wid = tid >> 6;
  int lane = tid & 63;
  int half = lane >> 5;
  int k = lane & 31;                         // neighbor slot
  int node = blockIdx.x * 8 + wid * 2 + half;  // always < N_NODES (exact grid)

  // coalesced adj load: each half reads one 128B adj row
  int nbr = adj[(size_t)node * DEGREE + k];

  // gather the full neighbor row: 16B (cols 0-7) + 2B (col 8), same 32B line
  const __hip_bfloat16* rp = featb + (size_t)nbr * FPAD;
  uint4 r = *(const uint4*)rp;
  unsigned short c8 = *(const unsigned short*)(rp + 8);

  float v[FEAT];
  v[0] = bflo(r.x); v[1] = bfhi(r.x);
  v[2] = bflo(r.y); v[3] = bfhi(r.y);
  v[4] = bflo(r.z); v[5] = bfhi(r.z);
  v[6] = bflo(r.w); v[7] = bfhi(r.w);
  v[8] = bflo((unsigned int)c8);

  // butterfly sum over the 32 lanes of each half (masks <=16 stay in-half)
#pragma unroll
  for (int m = 1; m <= 16; m <<= 1) {
#pragma unroll
    for (int j = 0; j < FEAT; ++j) v[j] += __shfl_xor(v[j], m, 64);
  }
  // every lane of the half now holds all 9 neighbor-column sums

  if (k < HID) {
    // self feat stays fp32: broadcast loads (same addr within the half -> 1
    // transaction each, L1-resident)
    float self[FEAT];
#pragma unroll
    for (int j = 0; j < FEAT; ++j) self[j] = feat[(size_t)node * FEAT + j];
    float acc = 0.f;
#pragma unroll
    for (int j = 0; j < FEAT; ++j) acc += sW1[k * 2 * FEAT + j] * self[j];
#pragma unroll
    for (int j = 0; j < FEAT; ++j)
      acc += sW1[k * 2 * FEAT + FEAT + j] * (v[j] * (1.0f / DEGREE));
    sH[wid][half][k] = fmaxf(acc, 0.f);  // h1
  }
  // same-wave LDS write->read: HW executes DS ops in program order per wave;
  // the fence stops compiler reordering.
  __builtin_amdgcn_wave_barrier();
  if (k < NOUT) {
    float acc = 0.f;
#pragma unroll
    for (int i = 0; i < HID; ++i) acc += sW2[k * HID + i] * sH[wid][half][i];
    // linear t (relu comes after the enc2 mean); pad col 15 never read
    t_ws[(size_t)node * FPAD + k] = __float2bfloat16(acc);
  }
}

// ---------------------------------------------------------------------------
// K2: wave-parallel enc2 aggregation + pair MLP. One wave = 1 pair; half 0 =
// endpoint 0, half 1 = endpoint 1. Lane k loads neighbor k's full t row
// (2x uint4, one aligned 32B line); butterfly gives the 15 column sums; self
// row added via broadcast loads; then the 30-wide fc1 dot is split across
// the halves and combined with one shfl_xor(32). Entire pair is wave-local.
// grid*4 == N_PAIRS exactly (2048*4).
// ---------------------------------------------------------------------------
__global__ __launch_bounds__(256) void k_pair(
    const int* __restrict__ to_pred,
    const int* __restrict__ adj,
    const __hip_bfloat16* __restrict__ t_ws,
    const float* __restrict__ fc1_w,  // [15][30]
    const float* __restrict__ fc1_b,  // [15]
    const float* __restrict__ fc2_w,  // [1][15]
    const float* __restrict__ fc2_b,  // [1]
    float* __restrict__ out) {
  __shared__ float s1[15 * 30];
  __shared__ float b1v[15];
  __shared__ float s2v[15];
  __shared__ float b2v;

  int tid = threadIdx.x;
  for (int i = tid; i < 15 * 30; i += 256) s1[i] = fc1_w[i];
  if (tid < 15) {
    b1v[tid] = fc1_b[tid];
    s2v[tid] = fc2_w[tid];
  }
  if (tid == 0) b2v = fc2_b[0];
  __syncthreads();

  int wid = tid >> 6;
  int lane = tid & 63;
  int half = lane >> 5;
  int k = lane & 31;
  int pair = blockIdx.x * 4 + wid;  // always < N_PAIRS (exact grid)
  int node = to_pred[2 * pair + half];

  int nbr = adj[(size_t)node * DEGREE + k];
  const __hip_bfloat16* rp = t_ws + (size_t)nbr * FPAD;
  uint4 a = *(const uint4*)rp;        // cols 0-7
  uint4 b = *(const uint4*)(rp + 8);  // cols 8-14 (+pad)

  float w[NOUT];
  w[0] = bflo(a.x);  w[1] = bfhi(a.x);
  w[2] = bflo(a.y);  w[3] = bfhi(a.y);
  w[4] = bflo(a.z);  w[5] = bfhi(a.z);
  w[6] = bflo(a.w);  w[7] = bfhi(a.w);
  w[8] = bflo(b.x);  w[9] = bfhi(b.x);
  w[10] = bflo(b.y); w[11] = bfhi(b.y);
  w[12] = bflo(b.z); w[13] = bfhi(b.z);
  w[14] = bflo(b.w);                   // skip pad col 15

#pragma unroll
  for (int m = 1; m <= 16; m <<= 1) {
#pragma unroll
    for (int j = 0; j < NOUT; ++j) w[j] += __shfl_xor(w[j], m, 64);
  }

  // self row (gcn=True): broadcast loads, same addr within the half
  const __hip_bfloat16* sp = t_ws + (size_t)node * FPAD;
  uint4 sa = *(const uint4*)sp;
  uint4 sb = *(const uint4*)(sp + 8);
  float e[NOUT];
  {
    float sv[NOUT];
    sv[0] = bflo(sa.x);  sv[1] = bfhi(sa.x);
    sv[2] = bflo(sa.y);  sv[3] = bfhi(sa.y);
    sv[4] = bflo(sa.z);  sv[5] = bfhi(sa.z);
    sv[6] = bflo(sa.w);  sv[7] = bfhi(sa.w);
    sv[8] = bflo(sb.x);  sv[9] = bfhi(sb.x);
    sv[10] = bflo(sb.y); sv[11] = bfhi(sb.y);
    sv[12] = bflo(sb.z); sv[13] = bfhi(sb.z);
    sv[14] = bflo(sb.w);
#pragma unroll
    for (int j = 0; j < NOUT; ++j)
      e[j] = fmaxf((w[j] + sv[j]) * (1.0f / (DEGREE + 1)), 0.f);
  }
  // e[] = this half's endpoint embedding, replicated across the half's lanes

  // fc1: h[i] = relu(b1[i] + fc1[i][0:15].e0 + fc1[i][15:30].e1)
  // lane i of half h computes the half's partial; one xor-32 shuffle combines.
  float p = (k < 15 && half == 0) ? b1v[k] : 0.f;
  if (k < 15) {
#pragma unroll
    for (int j = 0; j < 15; ++j) p += s1[k * 30 + half * 15 + j] * e[j];
  }
  float pOther = __shfl_xor(p, 32, 64);
  float h = fmaxf(p + pOther, 0.f);  // valid on lanes k<15 of both halves

  // fc2: out = relu(b2 + sum_k s2[k]*h[k]) — butterfly within the half
  float q = (k < 15) ? s2v[k] * h : 0.f;
#pragma unroll
  for (int m = 1; m <= 16; m <<= 1) q += __shfl_xor(q, m, 64);
  if (lane == 0) out[pair] = fmaxf(b2v + q, 0.f);
}

// ---------------------------------------------------------------------------
extern "C" void kernel_launch(void* const* d_in, const int* in_sizes, int n_in,
                              void* d_out, int out_size, void* d_ws,
                              size_t ws_size, hipStream_t stream) {
  const int* to_pred = (const int*)d_in[0];
  const int* adj     = (const int*)d_in[1];
  const float* feat  = (const float*)d_in[2];
  const float* W1    = (const float*)d_in[3];
  const float* W2    = (const float*)d_in[4];
  const float* fc1_w = (const float*)d_in[5];
  const float* fc1_b = (const float*)d_in[6];
  const float* fc2_w = (const float*)d_in[7];
  const float* fc2_b = (const float*)d_in[8];
  float* out         = (float*)d_out;

  // workspace: featb [100000][16] bf16 (3.2 MB) | t [100000][16] bf16 (3.2 MB)
  __hip_bfloat16* featb = (__hip_bfloat16*)d_ws;
  __hip_bfloat16* t_ws  = featb + (size_t)N_NODES * FPAD;

  int grid0 = (N_NODES + 255) / 256;  // 391
  k_prep<<<grid0, 256, 0, stream>>>(feat, featb);

  int grid1 = N_NODES / 8;            // 12500, exact (8 nodes per block)
  k_node<<<grid1, 256, 0, stream>>>(adj, feat, featb, W1, W2, t_ws);

  int grid2 = N_PAIRS / 4;            // 2048, exact (4 pairs per block)
  k_pair<<<grid2, 256, 0, stream>>>(to_pred, adj, t_ws, fc1_w, fc1_b,
                                    fc2_w, fc2_b, out);
}